// Round 14
// baseline (1269.309 us; speedup 1.0000x reference)
//
#include <hip/hip_runtime.h>

#define SQ     2048
#define DMODEL 2048
#define NHEAD  16
#define NKV    4
#define HDIM   128
#define FFDIM  5632
#define VOCAB  32000
#define NLAYER 2
#define EPSV   1e-5f

typedef __bf16 bf16;
typedef __bf16 bf16x4 __attribute__((ext_vector_type(4)));
typedef __bf16 bf16x8 __attribute__((ext_vector_type(8)));
typedef float  f32x4  __attribute__((ext_vector_type(4)));

enum { EP_STOREF = 0, EP_ADD = 2, EP_STOREB = 3, EP_QKV = 6, EP_GLU = 7, EP_ATOMIC = 8 };

// global -> LDS direct DMA, 16B per lane; LDS dest = wave-uniform base + lane*16
#define GLD(gp, lp) __builtin_amdgcn_global_load_lds( \
    (const __attribute__((address_space(1))) void*)(gp), \
    (__attribute__((address_space(3))) void*)(lp), 16, 0, 0)

#define MFMA16(a, b, c) __builtin_amdgcn_mfma_f32_16x16x32_bf16(a, b, c, 0, 0, 0)

#define FENCE() __builtin_amdgcn_sched_barrier(0)
#define PH_BAR() do { FENCE(); __builtin_amdgcn_s_barrier(); FENCE(); } while (0)

// XCD-bijective swizzle + m-fastest decode (m204)
#define XCD_SWZ(TM)                                                        \
  const int GM  = (int)gridDim.x;                                          \
  const int nwg = GM * (int)gridDim.y;                                     \
  const int bid = (int)blockIdx.y * GM + (int)blockIdx.x;                  \
  const int q8  = nwg >> 3, r8 = nwg & 7;                                  \
  const int xcd = bid & 7, rnk = bid >> 3;                                 \
  const int swz = ((xcd < r8) ? xcd * (q8 + 1)                             \
                              : r8 * (q8 + 1) + (xcd - r8) * q8) + rnk;    \
  const int m0  = (swz % GM) * (TM);                                       \
  const int n0  = (swz / GM) * (TM == 256 ? 256 : 128);

// ============================================================================
// 128x128-tile, BK=64, 4-wave, prefetching pipelined GEMM with optional
// split-K over blockIdx.z (EP_ATOMIC: partials unsafeAtomicAdd'ed into C).
// B-fragment rows relabeled to n*32 + wn*16 + colc so RoPE partner columns
// (d, d+64) live in the same thread (acc[m][n] <-> acc[m][n+2]).
// ============================================================================
template<int EPI, int NBUF>
__global__ __launch_bounds__(256, NBUF == 2 ? 2 : 1)
void gemm128(const bf16* __restrict__ A, const bf16* __restrict__ B,
             void* __restrict__ C, const void* __restrict__ Cin,
             bf16* __restrict__ C2, bf16* __restrict__ C3,
             const float* __restrict__ cosT, const float* __restrict__ sinT,
             int K, int lda, int ldb, int ldc)
{
  __shared__ bf16 As[NBUF][128 * 64];
  __shared__ bf16 Bs[NBUF][128 * 64];

  const int tid  = (int)threadIdx.x;
  const int lane = tid & 63;
  const int wave = tid >> 6;
  const int wm   = wave >> 1, wn = wave & 1;

  XCD_SWZ(128)

  const int z    = (int)blockIdx.z;
  const int nkt  = (K >> 6) / (int)gridDim.z;   // K-tiles this z-slice
  const int kt0  = z * nkt;
  const int srow = lane >> 3;
  const long sxcol = (long)(((lane & 7) ^ (lane >> 3)) * 8);
  const int colc = lane & 15;
  const int g4   = lane >> 4;

  auto stage = [&](int t, int buf) {
    if (t < nkt) {
      const long kc = (long)(kt0 + t) * 64 + sxcol;
      bf16* dA = As[buf];
      bf16* dB = Bs[buf];
      #pragma unroll
      for (int c = 0; c < 4; ++c) {
        const int chunk = wave * 4 + c;       // 16 chunks of 8 rows x 64 cols
        const int row   = chunk * 8 + srow;
        GLD(A + (long)(m0 + row) * lda + kc, dA + chunk * 512);
        GLD(B + (long)(n0 + row) * ldb + kc, dB + chunk * 512);
      }
    }
  };

  stage(0, 0);
  if (NBUF == 3) stage(1, 1);

  f32x4 acc[4][4] = {};
  int wb = (NBUF == 3) ? 2 : 1;               // buffer for next stage
  int rb = 0;                                 // buffer being read

  for (int t = 0; t < nkt; ++t) {
    if (NBUF == 2) {
      stage(t + 1, wb);
      wb ^= 1;
      FENCE();
      if (t + 1 < nkt) asm volatile("s_waitcnt vmcnt(8)" ::: "memory");
      else             asm volatile("s_waitcnt vmcnt(0)" ::: "memory");
    } else {
      stage(t + 2, wb);
      wb = (wb == 2) ? 0 : wb + 1;
      FENCE();
      if (t + 2 < nkt)      asm volatile("s_waitcnt vmcnt(16)" ::: "memory");
      else if (t + 1 < nkt) asm volatile("s_waitcnt vmcnt(8)"  ::: "memory");
      else                  asm volatile("s_waitcnt vmcnt(0)"  ::: "memory");
    }
    PH_BAR();
    const char* Ab = (const char*)As[rb];
    const char* Bb = (const char*)Bs[rb];
    rb = (NBUF == 2) ? (rb ^ 1) : ((rb == 2) ? 0 : rb + 1);
    #pragma unroll
    for (int kk = 0; kk < 2; ++kk) {
      bf16x8 af[4], bv[4];
      #pragma unroll
      for (int m = 0; m < 4; ++m) {
        const int r = wm * 64 + m * 16 + colc;
        af[m] = *(const bf16x8*)(Ab + r * 128 + (((kk * 4 + g4) ^ (r & 7)) * 16));
      }
      #pragma unroll
      for (int n = 0; n < 4; ++n) {
        const int r = n * 32 + wn * 16 + colc;   // relabeled (rope pairs in-thread)
        bv[n] = *(const bf16x8*)(Bb + r * 128 + (((kk * 4 + g4) ^ (r & 7)) * 16));
      }
      #pragma unroll
      for (int m = 0; m < 4; ++m)
        #pragma unroll
        for (int n = 0; n < 4; ++n)
          acc[m][n] = MFMA16(af[m], bv[n], acc[m][n]);
    }
    PH_BAR();
  }

  // epilogue. C/D frag: col = lane&15, row = (lane>>4)*4 + reg
  if (EPI == EP_QKV && n0 < 2560) {
    // q (n0 < 2048) or k: apply RoPE in-register; pair (n, n+2) = (d, d+64)
    #pragma unroll
    for (int m = 0; m < 4; ++m) {
      const int gr0 = m0 + wm * 64 + m * 16 + g4 * 4;
      #pragma unroll
      for (int n = 0; n < 2; ++n) {
        const int i   = n * 32 + wn * 16 + colc;   // head-dim index, < 64
        const int gc1 = n0 + i;
        #pragma unroll
        for (int r = 0; r < 4; ++r) {
          const int row = gr0 + r;
          const float c  = cosT[row * 64 + i];
          const float sn = sinT[row * 64 + i];
          const float x1 = acc[m][n][r];
          const float x2 = acc[m][n + 2][r];
          const float y1 = x1 * c - x2 * sn;
          const float y2 = x2 * c + x1 * sn;
          if (n0 < 2048) {
            bf16* q = (bf16*)C + (long)row * DMODEL;
            q[gc1] = (bf16)y1; q[gc1 + 64] = (bf16)y2;
          } else {
            bf16* k = C2 + (long)row * 512 + (gc1 - 2048);
            k[0] = (bf16)y1; k[64] = (bf16)y2;
          }
        }
      }
    }
    return;
  }

  #pragma unroll
  for (int m = 0; m < 4; ++m) {
    const int gr0 = m0 + wm * 64 + m * 16 + g4 * 4;
    #pragma unroll
    for (int n = 0; n < 4; ++n) {
      const int gc = n0 + n * 32 + wn * 16 + colc;
      if (EPI == EP_QKV) {                      // V region: transposed store
        bf16x4 pk = { (bf16)acc[m][n][0], (bf16)acc[m][n][1],
                      (bf16)acc[m][n][2], (bf16)acc[m][n][3] };
        *(bf16x4*)(C3 + (long)(gc - 2560) * SQ + gr0) = pk;
      } else if (EPI == EP_GLU) {
        #pragma unroll
        for (int r = 0; r < 4; ++r) {
          const float v = acc[m][n][r];
          const float o = __shfl_xor(v, 1);     // partner column's value
          if ((colc & 1) == 0) {                // even col lane: v=gate, o=up
            const float res = (o / (1.0f + __expf(-o))) * v;
            ((bf16*)C)[(long)(gr0 + r) * ldc + (gc >> 1)] = (bf16)res;
          }
        }
      } else if (EPI == EP_ATOMIC) {
        #pragma unroll
        for (int r = 0; r < 4; ++r)
          unsafeAtomicAdd((float*)C + (long)(gr0 + r) * ldc + gc, acc[m][n][r]);
      } else {
        #pragma unroll
        for (int r = 0; r < 4; ++r) {
          const long off = (long)(gr0 + r) * ldc + gc;
          const float v = acc[m][n][r];
          if (EPI == EP_STOREF)      ((float*)C)[off] = v;
          else if (EPI == EP_ADD)    ((float*)C)[off] = ((const float*)Cin)[off] + v;
          else if (EPI == EP_STOREB) ((bf16*)C)[off] = (bf16)v;
        }
      }
    }
  }
}

// ============================================================================
// 256x256-tile, BK=64, 8-wave, 4-phase/K-tile pipelined GEMM (T2+T3+T4+T5).
// Round-8 schedule (measured ~282us lm_head) — do not touch.
// ============================================================================
template<int EPI>
__global__ __launch_bounds__(512, 2)
void gemm256(const bf16* __restrict__ A, const bf16* __restrict__ B,
             void* __restrict__ C, const void* __restrict__ Cin,
             int K, int lda, int ldb, int ldc)
{
  __shared__ bf16 smem[2][4][128 * 64];   // 128 KiB

  const int tid  = (int)threadIdx.x;
  const int lane = tid & 63;
  const int wave = tid >> 6;
  const int wm   = wave >> 2;
  const int wn   = wave & 3;

  XCD_SWZ(256)

  const int nkt  = K >> 6;
  const int srow = lane >> 3;
  const long sxcol = (long)(((lane & 7) ^ (lane >> 3)) * 8);
  const int frow = lane & 15;
  const int ph0  = ((     (lane >> 4)) ^ (lane & 7)) * 16;
  const int ph1  = ((4 + (lane >> 4)) ^ (lane & 7)) * 16;

  auto stageA = [&](int tile, int half) {
    if (tile < nkt) {
      const long kc = (long)tile * 64 + sxcol;
      #pragma unroll
      for (int i = 0; i < 2; ++i)
        GLD(A + (long)(m0 + half * 128 + wave * 16 + i * 8 + srow) * lda + kc,
            smem[tile & 1][half] + (wave * 16 + i * 8) * 64);
    }
  };
  auto stageB = [&](int tile, int half) {
    if (tile < nkt) {
      const long kc = (long)tile * 64 + sxcol;
      #pragma unroll
      for (int i = 0; i < 2; ++i)
        GLD(B + (long)(n0 + half * 128 + wave * 16 + i * 8 + srow) * ldb + kc,
            smem[tile & 1][2 + half] + (wave * 16 + i * 8) * 64);
    }
  };

  stageB(0, 0); stageB(0, 1); stageA(0, 0); stageA(0, 1);
  asm volatile("s_waitcnt vmcnt(4)" ::: "memory");
  stageB(1, 0); stageB(1, 1); stageA(1, 0);
  asm volatile("s_waitcnt vmcnt(6)" ::: "memory");
  PH_BAR();

  f32x4 acc[8][4] = {};

  for (int t = 0; t < nkt; ++t) {
    const int bsel = t & 1;
    const char* Asl = (const char*)smem[bsel][wm];
    const char* Bsl = (const char*)smem[bsel][2 + (wn >> 1)];
    const int brow = (wn & 1) * 64;

    bf16x8 ar[4][2], b0f[2][2], b1f[2][2];

    #pragma unroll
    for (int mr = 0; mr < 4; ++mr) {
      ar[mr][0] = *(const bf16x8*)(Asl + (mr * 16 + frow) * 128 + ph0);
      ar[mr][1] = *(const bf16x8*)(Asl + (mr * 16 + frow) * 128 + ph1);
    }
    #pragma unroll
    for (int nc = 0; nc < 2; ++nc) {
      b0f[nc][0] = *(const bf16x8*)(Bsl + (brow + nc * 16 + frow) * 128 + ph0);
      b0f[nc][1] = *(const bf16x8*)(Bsl + (brow + nc * 16 + frow) * 128 + ph1);
    }
    stageA(t + 1, 1);
    PH_BAR();
    __builtin_amdgcn_s_setprio(1);
    #pragma unroll
    for (int mr = 0; mr < 4; ++mr)
      #pragma unroll
      for (int nc = 0; nc < 2; ++nc) {
        acc[mr][nc] = MFMA16(ar[mr][0], b0f[nc][0], acc[mr][nc]);
        acc[mr][nc] = MFMA16(ar[mr][1], b0f[nc][1], acc[mr][nc]);
      }
    __builtin_amdgcn_s_setprio(0);
    PH_BAR();

    #pragma unroll
    for (int nc = 0; nc < 2; ++nc) {
      b1f[nc][0] = *(const bf16x8*)(Bsl + (brow + (2 + nc) * 16 + frow) * 128 + ph0);
      b1f[nc][1] = *(const bf16x8*)(Bsl + (brow + (2 + nc) * 16 + frow) * 128 + ph1);
    }
    PH_BAR();
    __builtin_amdgcn_s_setprio(1);
    #pragma unroll
    for (int mr = 0; mr < 4; ++mr)
      #pragma unroll
      for (int nc = 0; nc < 2; ++nc) {
        acc[mr][2 + nc] = MFMA16(ar[mr][0], b1f[nc][0], acc[mr][2 + nc]);
        acc[mr][2 + nc] = MFMA16(ar[mr][1], b1f[nc][1], acc[mr][2 + nc]);
      }
    __builtin_amdgcn_s_setprio(0);
    PH_BAR();

    #pragma unroll
    for (int mr = 0; mr < 4; ++mr) {
      ar[mr][0] = *(const bf16x8*)(Asl + ((4 + mr) * 16 + frow) * 128 + ph0);
      ar[mr][1] = *(const bf16x8*)(Asl + ((4 + mr) * 16 + frow) * 128 + ph1);
    }
    stageB(t + 2, 0); stageB(t + 2, 1);
    PH_BAR();
    __builtin_amdgcn_s_setprio(1);
    #pragma unroll
    for (int mr = 0; mr < 4; ++mr)
      #pragma unroll
      for (int nc = 0; nc < 2; ++nc) {
        acc[4 + mr][nc] = MFMA16(ar[mr][0], b0f[nc][0], acc[4 + mr][nc]);
        acc[4 + mr][nc] = MFMA16(ar[mr][1], b0f[nc][1], acc[4 + mr][nc]);
      }
    __builtin_amdgcn_s_setprio(0);
    PH_BAR();

    stageA(t + 2, 0);
    PH_BAR();
    __builtin_amdgcn_s_setprio(1);
    #pragma unroll
    for (int mr = 0; mr < 4; ++mr)
      #pragma unroll
      for (int nc = 0; nc < 2; ++nc) {
        acc[4 + mr][2 + nc] = MFMA16(ar[mr][0], b1f[nc][0], acc[4 + mr][2 + nc]);
        acc[4 + mr][2 + nc] = MFMA16(ar[mr][1], b1f[nc][1], acc[4 + mr][2 + nc]);
      }
    __builtin_amdgcn_s_setprio(0);
    FENCE();
    if (t + 2 < nkt) asm volatile("s_waitcnt vmcnt(6)" ::: "memory");
    else             asm volatile("s_waitcnt vmcnt(0)" ::: "memory");
    PH_BAR();
  }

  #pragma unroll
  for (int mr = 0; mr < 8; ++mr) {
    const int gr0 = m0 + wm * 128 + mr * 16 + (lane >> 4) * 4;
    #pragma unroll
    for (int nc = 0; nc < 4; ++nc) {
      const int gc = n0 + wn * 64 + nc * 16 + (lane & 15);
      #pragma unroll
      for (int r = 0; r < 4; ++r) {
        const long off = (long)(gr0 + r) * ldc + gc;
        const float v = acc[mr][nc][r];
        if (EPI == EP_STOREF)      ((float*)C)[off] = v;
        else if (EPI == EP_STOREB) ((bf16*)C)[off] = (bf16)v;
      }
    }
  }
}

// ============================================================================
// Fused flash-style attention (mask-before-softmax, fixed-shift M=0 algebra).
// Round-10 version (best measured) — separate Ps buffer, 99 KB LDS, 1 block/CU.
// ============================================================================
__global__ __launch_bounds__(256, 1)
void flash_attn(const bf16* __restrict__ qb, const bf16* __restrict__ kb,
                const bf16* __restrict__ vT, const float* __restrict__ suffPc,
                bf16* __restrict__ yb, float scale)
{
  __shared__ bf16 Ks[128 * 128];
  __shared__ bf16 Vs[128 * 128];
  __shared__ bf16 Ps[128 * 136];

  const int tid  = (int)threadIdx.x;
  const int lane = tid & 63;
  const int w    = tid >> 6;
  const int qt   = (int)blockIdx.x;
  const int h    = (int)blockIdx.y;
  const int kvh  = h >> 2;

  const int l15 = lane & 15;
  const int g4  = lane >> 4;

  bf16x8 qf[2][4];
  #pragma unroll
  for (int m = 0; m < 2; ++m)
    #pragma unroll
    for (int ks = 0; ks < 4; ++ks)
      qf[m][ks] = *(const bf16x8*)(qb + (long)(qt * 128 + w * 32 + m * 16 + l15) * DMODEL
                                   + h * HDIM + ks * 32 + g4 * 8);

  f32x4 acc_o[2][8] = {};
  float den[2][4] = {};

  const bf16* Kg = kb + (long)kvh * HDIM;
  const bf16* Vg = vT + (long)(kvh * HDIM) * SQ;

  for (int j = 0; j <= qt; ++j) {
    const bool diag = (j == qt);
    PH_BAR();

    #pragma unroll
    for (int i = 0; i < 8; ++i) {
      const int rb = w * 32 + i * 4;
      const int r  = rb + g4;
      GLD(Kg + (long)(j * 128 + r) * 512 + ((l15 ^ (r & 7)) * 8), Ks + rb * 128);
    }
    #pragma unroll
    for (int i = 0; i < 8; ++i) {
      const int rb = w * 32 + i * 4;
      const int r  = rb + g4;
      GLD(Vg + (long)r * SQ + j * 128 + ((l15 ^ (r & 7)) * 8), Vs + rb * 128);
    }
    asm volatile("s_waitcnt vmcnt(8)" ::: "memory");
    PH_BAR();

    f32x4 acc_s[2][8] = {};
    #pragma unroll
    for (int ks = 0; ks < 4; ++ks) {
      bf16x8 kf[8];
      #pragma unroll
      for (int n = 0; n < 8; ++n) {
        const int kr = n * 16 + l15;
        kf[n] = *(const bf16x8*)((const char*)Ks + kr * 256 + (((ks * 4 + g4) ^ (kr & 7)) * 16));
      }
      #pragma unroll
      for (int m = 0; m < 2; ++m)
        #pragma unroll
        for (int n = 0; n < 8; ++n)
          acc_s[m][n] = MFMA16(qf[m][ks], kf[n], acc_s[m][n]);
    }

    float rs[2][4] = {};
    #pragma unroll
    for (int m = 0; m < 2; ++m)
      #pragma unroll
      for (int n = 0; n < 8; ++n) {
        const int kc = n * 16 + l15;
        #pragma unroll
        for (int r = 0; r < 4; ++r) {
          const int qlr = w * 32 + m * 16 + g4 * 4 + r;
          float p = __expf(acc_s[m][n][r] * scale);
          if (diag && kc > qlr) p = 1.0f;
          rs[m][r] += p;
          Ps[(w * 32 + m * 16 + g4 * 4 + r) * 136 + kc] = (bf16)p;
        }
      }
    #pragma unroll
    for (int m = 0; m < 2; ++m)
      #pragma unroll
      for (int r = 0; r < 4; ++r) {
        float v = rs[m][r];
        v += __shfl_xor(v, 1); v += __shfl_xor(v, 2);
        v += __shfl_xor(v, 4); v += __shfl_xor(v, 8);
        den[m][r] += v;
      }

    asm volatile("s_waitcnt vmcnt(0) lgkmcnt(0)" ::: "memory");
    PH_BAR();

    #pragma unroll
    for (int ks = 0; ks < 4; ++ks) {
      bf16x8 pa[2], vf[8];
      #pragma unroll
      for (int m = 0; m < 2; ++m)
        pa[m] = *(const bf16x8*)((const char*)Ps + (w * 32 + m * 16 + l15) * 272
                                 + ks * 64 + g4 * 16);
      #pragma unroll
      for (int n = 0; n < 8; ++n) {
        const int dr = n * 16 + l15;
        vf[n] = *(const bf16x8*)((const char*)Vs + dr * 256 + (((ks * 4 + g4) ^ (dr & 7)) * 16));
      }
      #pragma unroll
      for (int m = 0; m < 2; ++m)
        #pragma unroll
        for (int n = 0; n < 8; ++n)
          acc_o[m][n] = MFMA16(pa[m], vf[n], acc_o[m][n]);
    }
  }

  float denf[2][4];
  #pragma unroll
  for (int m = 0; m < 2; ++m)
    #pragma unroll
    for (int r = 0; r < 4; ++r)
      denf[m][r] = den[m][r] + 128.0f * (15 - qt);

  #pragma unroll
  for (int n = 0; n < 8; ++n) {
    const float t = suffPc[((kvh << 4) + qt) * 128 + n * 16 + l15];
    #pragma unroll
    for (int m = 0; m < 2; ++m)
      #pragma unroll
      for (int r = 0; r < 4; ++r) {
        const float y = (acc_o[m][n][r] + t) / denf[m][r];
        yb[(long)(qt * 128 + w * 32 + m * 16 + g4 * 4 + r) * DMODEL
           + h * HDIM + n * 16 + l15] = (bf16)y;
      }
  }
}

// per (kvh): suffPc[kvh][c][d] = sum over chunks c' > c of column-sums of V
__global__ __launch_bounds__(128)
void vsuffix(const bf16* __restrict__ vT, float* __restrict__ suffPc)
{
  const int kvh = (int)blockIdx.x;
  const int d   = (int)threadIdx.x;
  const bf16* row = vT + (long)(kvh * HDIM + d) * SQ;
  float a = 0.f;
  for (int c = 15; c >= 0; --c) {
    suffPc[(kvh * 16 + c) * 128 + d] = a;
    float s = 0.f;
    #pragma unroll
    for (int r = 0; r < 16; ++r) {
      bf16x8 v = *(const bf16x8*)(row + c * 128 + r * 8);
      #pragma unroll
      for (int e = 0; e < 8; ++e) s += (float)v[e];
    }
    a += s;
  }
}

// fp32 [K][N] -> bf16 transpose+convert, up to 4 segments (z-indexed).
__global__ __launch_bounds__(256)
void transpose_cvt4(const float* __restrict__ s0, bf16* __restrict__ d0, int N0, int L0,
                    const float* __restrict__ s1, bf16* __restrict__ d1, int N1, int L1,
                    const float* __restrict__ s2, bf16* __restrict__ d2, int N2, int L2,
                    const float* __restrict__ s3, bf16* __restrict__ d3, int N3, int L3,
                    int K)
{
  const float* src; bf16* dst; int N, L;
  if (blockIdx.z == 0)      { src = s0; dst = d0; N = N0; L = L0; }
  else if (blockIdx.z == 1) { src = s1; dst = d1; N = N1; L = L1; }
  else if (blockIdx.z == 2) { src = s2; dst = d2; N = N2; L = L2; }
  else                      { src = s3; dst = d3; N = N3; L = L3; }
  if (!src) return;
  const int n0 = (int)blockIdx.x * 32; if (n0 >= N) return;
  const int k0 = (int)blockIdx.y * 32;
  __shared__ float t[32][33];
  const int tr = (int)threadIdx.x >> 3;
  const int tc = ((int)threadIdx.x & 7) * 4;
  f32x4 v = *(const f32x4*)(src + (long)(k0 + tr) * N + n0 + tc);
  t[tr][tc] = v[0]; t[tr][tc + 1] = v[1]; t[tr][tc + 2] = v[2]; t[tr][tc + 3] = v[3];
  __syncthreads();
  bf16x4 b = { (bf16)t[tc][tr], (bf16)t[tc + 1][tr], (bf16)t[tc + 2][tr], (bf16)t[tc + 3][tr] };
  *(bf16x4*)(dst + (long)(n0 + tr) * L + k0 + tc) = b;
}

__global__ __launch_bounds__(256)
void cvt_bf16_kernel(const float* __restrict__ in, bf16* __restrict__ out, int nvec)
{
  const int i = (int)(blockIdx.x * 256 + threadIdx.x);
  if (i < nvec) {
    f32x4 v = ((const f32x4*)in)[i];
    bf16x4 b = { (bf16)v[0], (bf16)v[1], (bf16)v[2], (bf16)v[3] };
    ((bf16x4*)out)[i] = b;
  }
}

__global__ __launch_bounds__(256)
void rmsnorm_kernel(bf16* __restrict__ out, const float* __restrict__ in, const float* __restrict__ g)
{
  const int row = (int)blockIdx.x;
  const float* x = in + (long)row * DMODEL;
  bf16* o = out + (long)row * DMODEL;
  const int tid = (int)threadIdx.x;
  f32x4 v0 = *(const f32x4*)(x + tid * 4);
  f32x4 v1 = *(const f32x4*)(x + tid * 4 + 1024);
  float ss = v0[0]*v0[0] + v0[1]*v0[1] + v0[2]*v0[2] + v0[3]*v0[3]
           + v1[0]*v1[0] + v1[1]*v1[1] + v1[2]*v1[2] + v1[3]*v1[3];
  #pragma unroll
  for (int o_ = 32; o_; o_ >>= 1) ss += __shfl_xor(ss, o_);
  __shared__ float sm[4];
  if ((tid & 63) == 0) sm[tid >> 6] = ss;
  __syncthreads();
  ss = sm[0] + sm[1] + sm[2] + sm[3];
  const float r = 1.0f / sqrtf(ss * (1.0f / DMODEL) + EPSV);
  f32x4 g0 = *(const f32x4*)(g + tid * 4);
  f32x4 g1 = *(const f32x4*)(g + tid * 4 + 1024);
  bf16x4 o0, o1;
  #pragma unroll
  for (int j = 0; j < 4; ++j) { o0[j] = (bf16)(v0[j] * r * g0[j]); o1[j] = (bf16)(v1[j] * r * g1[j]); }
  *(bf16x4*)(o + tid * 4) = o0;
  *(bf16x4*)(o + tid * 4 + 1024) = o1;
}

__global__ void rope_tables(float* cosT, float* sinT)
{
  const int s = (int)blockIdx.x;
  const int i = (int)threadIdx.x;
  const double inv = pow(10000.0, -(double)i / 64.0);
  const double f = (double)s * inv;
  cosT[s * 64 + i] = (float)cos(f);
  sinT[s * 64 + i] = (float)sin(f);
}

__global__ __launch_bounds__(256)
void embed_gather(f32x4* x, const f32x4* embed, const int* idx)
{
  const int t = (int)(blockIdx.x * 256 + threadIdx.x);
  const int s = t >> 9;
  const int c = t & 511;
  x[t] = embed[(long)idx[s] * 512 + c];
}

extern "C" void kernel_launch(void* const* d_in, const int* in_sizes, int n_in,
                              void* d_out, int out_size, void* d_ws, size_t ws_size,
                              hipStream_t stream)
{
  (void)in_sizes; (void)n_in; (void)out_size;
  const int*   idx   = (const int*)  d_in[0];
  const float* embed = (const float*)d_in[1];
  const float* wq    = (const float*)d_in[2];
  const float* wk    = (const float*)d_in[3];
  const float* wv    = (const float*)d_in[4];
  const float* wo    = (const float*)d_in[5];
  const float* ln1g  = (const float*)d_in[6];
  const float* ln2g  = (const float*)d_in[7];
  const float* wgate = (const float*)d_in[8];
  const float* wup   = (const float*)d_in[9];
  const float* wdown = (const float*)d_in[10];
  const float* fing  = (const float*)d_in[11];
  const float* lmh   = (const float*)d_in[12];
  float* out = (float*)d_out;

  char* wp = (char*)d_ws;
  auto alloc = [&](size_t bytes) { char* p = wp; wp += (bytes + 255) & ~(size_t)255; return p; };
  float* cosT   = (float*)alloc((size_t)SQ * 64 * 4);
  float* sinT   = (float*)alloc((size_t)SQ * 64 * 4);
  float* suffPc = (float*)alloc((size_t)NKV * 16 * 128 * 4);
  float* x      = (float*)alloc((size_t)SQ * DMODEL * 4);
  bf16*  h      = (bf16*) alloc((size_t)SQ * DMODEL * 2);
  bf16*  qb     = (bf16*) alloc((size_t)SQ * DMODEL * 2);
  bf16*  kb     = (bf16*) alloc((size_t)SQ * 512 * 2);
  bf16*  vT     = (bf16*) alloc((size_t)512 * SQ * 2);
  bf16*  ffb    = (bf16*) alloc((size_t)SQ * FFDIM * 2);
  size_t used  = (size_t)(wp - (char*)d_ws);
  bf16*  wbuf  = (bf16*)wp;                 // weight scratch (peak: gate+up 46 MB)
  size_t avail = ws_size - used;

  bf16* yb = qb;                            // flash writes y over q (same rows per block)
  const float scale = 0.08838834764831845f;

  rope_tables<<<SQ, 64, 0, stream>>>(cosT, sinT);
  embed_gather<<<(SQ * 512) / 256, 256, 0, stream>>>((f32x4*)x, (const f32x4*)embed, idx);

  for (int l = 0; l < NLAYER; ++l) {
    const float* lwq = wq    + (long)l * DMODEL * DMODEL;
    const float* lwk = wk    + (long)l * DMODEL * 512;
    const float* lwv = wv    + (long)l * DMODEL * 512;
    const float* lwo = wo    + (long)l * DMODEL * DMODEL;
    const float* lwg = wgate + (long)l * DMODEL * FFDIM;
    const float* lwu = wup   + (long)l * DMODEL * FFDIM;
    const float* lwd = wdown + (long)l * FFDIM * DMODEL;

    rmsnorm_kernel<<<SQ, 256, 0, stream>>>(h, x, ln1g + l * DMODEL);

    // QKV + wo weight cvt in one dispatch: [wq^T | wk^T | wv^T | wo^T] (5120 x 2048, 21 MB)
    bf16* wob = wbuf + (long)3072 * DMODEL;
    transpose_cvt4<<<dim3(64, 64, 4), 256, 0, stream>>>(
        lwq, wbuf, DMODEL, DMODEL,
        lwk, wbuf + (long)2048 * DMODEL, 512, DMODEL,
        lwv, wbuf + (long)2560 * DMODEL, 512, DMODEL,
        lwo, wob, DMODEL, DMODEL, DMODEL);
    // QKV GEMM with in-epilogue RoPE for q and k
    gemm128<EP_QKV, 2><<<dim3(16, 24), 256, 0, stream>>>(
        h, wbuf, qb, nullptr, kb, vT, cosT, sinT, DMODEL, DMODEL, DMODEL, 0);

    vsuffix<<<NKV, 128, 0, stream>>>(vT, suffPc);

    flash_attn<<<dim3(16, NHEAD), 256, 0, stream>>>(qb, kb, vT, suffPc, yb, scale);

    // x += y @ wo  — split-K=2, fp32 atomics into x (in place)
    gemm128<EP_ATOMIC, 2><<<dim3(16, 16, 2), 256, 0, stream>>>(
        yb, wob, x, nullptr, nullptr, nullptr, nullptr, nullptr,
        DMODEL, DMODEL, DMODEL, DMODEL);

    rmsnorm_kernel<<<SQ, 256, 0, stream>>>(h, x, ln2g + l * DMODEL);

    // gate+up interleaved: even rows = wg^T, odd rows = wu^T (11264 x 2048)
    transpose_cvt4<<<dim3(176, 64, 2), 256, 0, stream>>>(
        lwg, wbuf, FFDIM, 2 * DMODEL,
        lwu, wbuf + DMODEL, FFDIM, 2 * DMODEL,
        nullptr, nullptr, 0, 0, nullptr, nullptr, 0, 0, DMODEL);
    gemm128<EP_GLU, 2><<<dim3(16, 88), 256, 0, stream>>>(
        h, wbuf, ffb, nullptr, nullptr, nullptr, nullptr, nullptr,
        DMODEL, DMODEL, DMODEL, FFDIM);

    // x += ffb @ w_down — split-K=2, fp32 atomics into x (in place)
    transpose_cvt4<<<dim3(64, 176, 1), 256, 0, stream>>>(
        lwd, wbuf, DMODEL, FFDIM,
        nullptr, nullptr, 0, 0, nullptr, nullptr, 0, 0,
        nullptr, nullptr, 0, 0, FFDIM);
    gemm128<EP_ATOMIC, 2><<<dim3(16, 16, 2), 256, 0, stream>>>(
        ffb, wbuf, x, nullptr, nullptr, nullptr, nullptr, nullptr,
        FFDIM, FFDIM, FFDIM, DMODEL);
  }

  rmsnorm_kernel<<<SQ, 256, 0, stream>>>(h, x, fing);

  long chunkRows = (long)(avail / ((size_t)DMODEL * 2)) & ~255L;
  if (chunkRows > VOCAB) chunkRows = VOCAB;
  for (long c0 = 0; c0 < VOCAB; c0 += chunkRows) {
    const long rows = (VOCAB - c0 < chunkRows) ? (VOCAB - c0) : chunkRows;
    const int  nvec = (int)(rows * DMODEL / 4);
    cvt_bf16_kernel<<<(nvec + 255) / 256, 256, 0, stream>>>(lmh + c0 * DMODEL, wbuf, nvec);
    gemm256<EP_STOREF><<<dim3(8, (int)(rows / 256)), 512, 0, stream>>>(
        h, wbuf, out + c0, nullptr, DMODEL, DMODEL, DMODEL, VOCAB);
  }
}

// Round 15
// 1207.223 us; speedup vs baseline: 1.0514x; 1.0514x over previous
//
#include <hip/hip_runtime.h>

#define SQ     2048
#define DMODEL 2048
#define NHEAD  16
#define NKV    4
#define HDIM   128
#define FFDIM  5632
#define VOCAB  32000
#define NLAYER 2
#define EPSV   1e-5f

typedef __bf16 bf16;
typedef __bf16 bf16x4 __attribute__((ext_vector_type(4)));
typedef __bf16 bf16x8 __attribute__((ext_vector_type(8)));
typedef float  f32x4  __attribute__((ext_vector_type(4)));

enum { EP_STOREF = 0, EP_ADD = 2, EP_STOREB = 3, EP_QKV = 6, EP_GLU = 7, EP_ATOMIC = 8 };

// global -> LDS direct DMA, 16B per lane; LDS dest = wave-uniform base + lane*16
#define GLD(gp, lp) __builtin_amdgcn_global_load_lds( \
    (const __attribute__((address_space(1))) void*)(gp), \
    (__attribute__((address_space(3))) void*)(lp), 16, 0, 0)

#define MFMA16(a, b, c) __builtin_amdgcn_mfma_f32_16x16x32_bf16(a, b, c, 0, 0, 0)

#define FENCE() __builtin_amdgcn_sched_barrier(0)
#define PH_BAR() do { FENCE(); __builtin_amdgcn_s_barrier(); FENCE(); } while (0)

// XCD-bijective swizzle + m-fastest decode (m204)
#define XCD_SWZ(TM)                                                        \
  const int GM  = (int)gridDim.x;                                          \
  const int nwg = GM * (int)gridDim.y;                                     \
  const int bid = (int)blockIdx.y * GM + (int)blockIdx.x;                  \
  const int q8  = nwg >> 3, r8 = nwg & 7;                                  \
  const int xcd = bid & 7, rnk = bid >> 3;                                 \
  const int swz = ((xcd < r8) ? xcd * (q8 + 1)                             \
                              : r8 * (q8 + 1) + (xcd - r8) * q8) + rnk;    \
  const int m0  = (swz % GM) * (TM);                                       \
  const int n0  = (swz / GM) * (TM == 256 ? 256 : 128);

// ============================================================================
// 128x128-tile, BK=64, 4-wave, prefetching pipelined GEMM with optional
// split-K over blockIdx.z (EP_ATOMIC: partials unsafeAtomicAdd'ed into C).
// B-fragment rows relabeled to n*32 + wn*16 + colc so RoPE partner columns
// (d, d+64) live in the same thread (acc[m][n] <-> acc[m][n+2]).
// ============================================================================
template<int EPI, int NBUF>
__global__ __launch_bounds__(256, NBUF == 2 ? 2 : 1)
void gemm128(const bf16* __restrict__ A, const bf16* __restrict__ B,
             void* __restrict__ C, const void* __restrict__ Cin,
             bf16* __restrict__ C2, bf16* __restrict__ C3,
             const float* __restrict__ cosT, const float* __restrict__ sinT,
             int K, int lda, int ldb, int ldc)
{
  __shared__ bf16 As[NBUF][128 * 64];
  __shared__ bf16 Bs[NBUF][128 * 64];

  const int tid  = (int)threadIdx.x;
  const int lane = tid & 63;
  const int wave = tid >> 6;
  const int wm   = wave >> 1, wn = wave & 1;

  XCD_SWZ(128)

  const int z    = (int)blockIdx.z;
  const int nkt  = (K >> 6) / (int)gridDim.z;   // K-tiles this z-slice
  const int kt0  = z * nkt;
  const int srow = lane >> 3;
  const long sxcol = (long)(((lane & 7) ^ (lane >> 3)) * 8);
  const int colc = lane & 15;
  const int g4   = lane >> 4;

  auto stage = [&](int t, int buf) {
    if (t < nkt) {
      const long kc = (long)(kt0 + t) * 64 + sxcol;
      bf16* dA = As[buf];
      bf16* dB = Bs[buf];
      #pragma unroll
      for (int c = 0; c < 4; ++c) {
        const int chunk = wave * 4 + c;       // 16 chunks of 8 rows x 64 cols
        const int row   = chunk * 8 + srow;
        GLD(A + (long)(m0 + row) * lda + kc, dA + chunk * 512);
        GLD(B + (long)(n0 + row) * ldb + kc, dB + chunk * 512);
      }
    }
  };

  stage(0, 0);
  if (NBUF == 3) stage(1, 1);

  f32x4 acc[4][4] = {};
  int wb = (NBUF == 3) ? 2 : 1;               // buffer for next stage
  int rb = 0;                                 // buffer being read

  for (int t = 0; t < nkt; ++t) {
    if (NBUF == 2) {
      stage(t + 1, wb);
      wb ^= 1;
      FENCE();
      if (t + 1 < nkt) asm volatile("s_waitcnt vmcnt(8)" ::: "memory");
      else             asm volatile("s_waitcnt vmcnt(0)" ::: "memory");
    } else {
      stage(t + 2, wb);
      wb = (wb == 2) ? 0 : wb + 1;
      FENCE();
      if (t + 2 < nkt)      asm volatile("s_waitcnt vmcnt(16)" ::: "memory");
      else if (t + 1 < nkt) asm volatile("s_waitcnt vmcnt(8)"  ::: "memory");
      else                  asm volatile("s_waitcnt vmcnt(0)"  ::: "memory");
    }
    PH_BAR();
    const char* Ab = (const char*)As[rb];
    const char* Bb = (const char*)Bs[rb];
    rb = (NBUF == 2) ? (rb ^ 1) : ((rb == 2) ? 0 : rb + 1);
    #pragma unroll
    for (int kk = 0; kk < 2; ++kk) {
      bf16x8 af[4], bv[4];
      #pragma unroll
      for (int m = 0; m < 4; ++m) {
        const int r = wm * 64 + m * 16 + colc;
        af[m] = *(const bf16x8*)(Ab + r * 128 + (((kk * 4 + g4) ^ (r & 7)) * 16));
      }
      #pragma unroll
      for (int n = 0; n < 4; ++n) {
        const int r = n * 32 + wn * 16 + colc;   // relabeled (rope pairs in-thread)
        bv[n] = *(const bf16x8*)(Bb + r * 128 + (((kk * 4 + g4) ^ (r & 7)) * 16));
      }
      #pragma unroll
      for (int m = 0; m < 4; ++m)
        #pragma unroll
        for (int n = 0; n < 4; ++n)
          acc[m][n] = MFMA16(af[m], bv[n], acc[m][n]);
    }
    PH_BAR();
  }

  // epilogue. C/D frag: col = lane&15, row = (lane>>4)*4 + reg
  if (EPI == EP_QKV && n0 < 2560) {
    // q (n0 < 2048) or k: apply RoPE in-register; pair (n, n+2) = (d, d+64)
    #pragma unroll
    for (int m = 0; m < 4; ++m) {
      const int gr0 = m0 + wm * 64 + m * 16 + g4 * 4;
      #pragma unroll
      for (int n = 0; n < 2; ++n) {
        const int i   = n * 32 + wn * 16 + colc;   // head-dim index, < 64
        const int gc1 = n0 + i;
        #pragma unroll
        for (int r = 0; r < 4; ++r) {
          const int row = gr0 + r;
          const float c  = cosT[row * 64 + i];
          const float sn = sinT[row * 64 + i];
          const float x1 = acc[m][n][r];
          const float x2 = acc[m][n + 2][r];
          const float y1 = x1 * c - x2 * sn;
          const float y2 = x2 * c + x1 * sn;
          if (n0 < 2048) {
            bf16* q = (bf16*)C + (long)row * DMODEL;
            q[gc1] = (bf16)y1; q[gc1 + 64] = (bf16)y2;
          } else {
            bf16* k = C2 + (long)row * 512 + (gc1 - 2048);
            k[0] = (bf16)y1; k[64] = (bf16)y2;
          }
        }
      }
    }
    return;
  }

  #pragma unroll
  for (int m = 0; m < 4; ++m) {
    const int gr0 = m0 + wm * 64 + m * 16 + g4 * 4;
    #pragma unroll
    for (int n = 0; n < 4; ++n) {
      const int gc = n0 + n * 32 + wn * 16 + colc;
      if (EPI == EP_QKV) {                      // V region: transposed store
        bf16x4 pk = { (bf16)acc[m][n][0], (bf16)acc[m][n][1],
                      (bf16)acc[m][n][2], (bf16)acc[m][n][3] };
        *(bf16x4*)(C3 + (long)(gc - 2560) * SQ + gr0) = pk;
      } else if (EPI == EP_GLU) {
        #pragma unroll
        for (int r = 0; r < 4; ++r) {
          const float v = acc[m][n][r];
          const float o = __shfl_xor(v, 1);     // partner column's value
          if ((colc & 1) == 0) {                // even col lane: v=gate, o=up
            const float res = (o / (1.0f + __expf(-o))) * v;
            ((bf16*)C)[(long)(gr0 + r) * ldc + (gc >> 1)] = (bf16)res;
          }
        }
      } else if (EPI == EP_ATOMIC) {
        #pragma unroll
        for (int r = 0; r < 4; ++r)
          unsafeAtomicAdd((float*)C + (long)(gr0 + r) * ldc + gc, acc[m][n][r]);
      } else {
        #pragma unroll
        for (int r = 0; r < 4; ++r) {
          const long off = (long)(gr0 + r) * ldc + gc;
          const float v = acc[m][n][r];
          if (EPI == EP_STOREF)      ((float*)C)[off] = v;
          else if (EPI == EP_ADD)    ((float*)C)[off] = ((const float*)Cin)[off] + v;
          else if (EPI == EP_STOREB) ((bf16*)C)[off] = (bf16)v;
        }
      }
    }
  }
}

// ============================================================================
// 256x256-tile, BK=64, 8-wave, 4-phase/K-tile pipelined GEMM (T2+T3+T4+T5).
// Round-8 schedule (measured ~282us lm_head) — do not touch.
// ============================================================================
template<int EPI>
__global__ __launch_bounds__(512, 2)
void gemm256(const bf16* __restrict__ A, const bf16* __restrict__ B,
             void* __restrict__ C, const void* __restrict__ Cin,
             int K, int lda, int ldb, int ldc)
{
  __shared__ bf16 smem[2][4][128 * 64];   // 128 KiB

  const int tid  = (int)threadIdx.x;
  const int lane = tid & 63;
  const int wave = tid >> 6;
  const int wm   = wave >> 2;
  const int wn   = wave & 3;

  XCD_SWZ(256)

  const int nkt  = K >> 6;
  const int srow = lane >> 3;
  const long sxcol = (long)(((lane & 7) ^ (lane >> 3)) * 8);
  const int frow = lane & 15;
  const int ph0  = ((     (lane >> 4)) ^ (lane & 7)) * 16;
  const int ph1  = ((4 + (lane >> 4)) ^ (lane & 7)) * 16;

  auto stageA = [&](int tile, int half) {
    if (tile < nkt) {
      const long kc = (long)tile * 64 + sxcol;
      #pragma unroll
      for (int i = 0; i < 2; ++i)
        GLD(A + (long)(m0 + half * 128 + wave * 16 + i * 8 + srow) * lda + kc,
            smem[tile & 1][half] + (wave * 16 + i * 8) * 64);
    }
  };
  auto stageB = [&](int tile, int half) {
    if (tile < nkt) {
      const long kc = (long)tile * 64 + sxcol;
      #pragma unroll
      for (int i = 0; i < 2; ++i)
        GLD(B + (long)(n0 + half * 128 + wave * 16 + i * 8 + srow) * ldb + kc,
            smem[tile & 1][2 + half] + (wave * 16 + i * 8) * 64);
    }
  };

  stageB(0, 0); stageB(0, 1); stageA(0, 0); stageA(0, 1);
  asm volatile("s_waitcnt vmcnt(4)" ::: "memory");
  stageB(1, 0); stageB(1, 1); stageA(1, 0);
  asm volatile("s_waitcnt vmcnt(6)" ::: "memory");
  PH_BAR();

  f32x4 acc[8][4] = {};

  for (int t = 0; t < nkt; ++t) {
    const int bsel = t & 1;
    const char* Asl = (const char*)smem[bsel][wm];
    const char* Bsl = (const char*)smem[bsel][2 + (wn >> 1)];
    const int brow = (wn & 1) * 64;

    bf16x8 ar[4][2], b0f[2][2], b1f[2][2];

    #pragma unroll
    for (int mr = 0; mr < 4; ++mr) {
      ar[mr][0] = *(const bf16x8*)(Asl + (mr * 16 + frow) * 128 + ph0);
      ar[mr][1] = *(const bf16x8*)(Asl + (mr * 16 + frow) * 128 + ph1);
    }
    #pragma unroll
    for (int nc = 0; nc < 2; ++nc) {
      b0f[nc][0] = *(const bf16x8*)(Bsl + (brow + nc * 16 + frow) * 128 + ph0);
      b0f[nc][1] = *(const bf16x8*)(Bsl + (brow + nc * 16 + frow) * 128 + ph1);
    }
    stageA(t + 1, 1);
    PH_BAR();
    __builtin_amdgcn_s_setprio(1);
    #pragma unroll
    for (int mr = 0; mr < 4; ++mr)
      #pragma unroll
      for (int nc = 0; nc < 2; ++nc) {
        acc[mr][nc] = MFMA16(ar[mr][0], b0f[nc][0], acc[mr][nc]);
        acc[mr][nc] = MFMA16(ar[mr][1], b0f[nc][1], acc[mr][nc]);
      }
    __builtin_amdgcn_s_setprio(0);
    PH_BAR();

    #pragma unroll
    for (int nc = 0; nc < 2; ++nc) {
      b1f[nc][0] = *(const bf16x8*)(Bsl + (brow + (2 + nc) * 16 + frow) * 128 + ph0);
      b1f[nc][1] = *(const bf16x8*)(Bsl + (brow + (2 + nc) * 16 + frow) * 128 + ph1);
    }
    PH_BAR();
    __builtin_amdgcn_s_setprio(1);
    #pragma unroll
    for (int mr = 0; mr < 4; ++mr)
      #pragma unroll
      for (int nc = 0; nc < 2; ++nc) {
        acc[mr][2 + nc] = MFMA16(ar[mr][0], b1f[nc][0], acc[mr][2 + nc]);
        acc[mr][2 + nc] = MFMA16(ar[mr][1], b1f[nc][1], acc[mr][2 + nc]);
      }
    __builtin_amdgcn_s_setprio(0);
    PH_BAR();

    #pragma unroll
    for (int mr = 0; mr < 4; ++mr) {
      ar[mr][0] = *(const bf16x8*)(Asl + ((4 + mr) * 16 + frow) * 128 + ph0);
      ar[mr][1] = *(const bf16x8*)(Asl + ((4 + mr) * 16 + frow) * 128 + ph1);
    }
    stageB(t + 2, 0); stageB(t + 2, 1);
    PH_BAR();
    __builtin_amdgcn_s_setprio(1);
    #pragma unroll
    for (int mr = 0; mr < 4; ++mr)
      #pragma unroll
      for (int nc = 0; nc < 2; ++nc) {
        acc[4 + mr][nc] = MFMA16(ar[mr][0], b0f[nc][0], acc[4 + mr][nc]);
        acc[4 + mr][nc] = MFMA16(ar[mr][1], b0f[nc][1], acc[4 + mr][nc]);
      }
    __builtin_amdgcn_s_setprio(0);
    PH_BAR();

    stageA(t + 2, 0);
    PH_BAR();
    __builtin_amdgcn_s_setprio(1);
    #pragma unroll
    for (int mr = 0; mr < 4; ++mr)
      #pragma unroll
      for (int nc = 0; nc < 2; ++nc) {
        acc[4 + mr][2 + nc] = MFMA16(ar[mr][0], b1f[nc][0], acc[4 + mr][2 + nc]);
        acc[4 + mr][2 + nc] = MFMA16(ar[mr][1], b1f[nc][1], acc[4 + mr][2 + nc]);
      }
    __builtin_amdgcn_s_setprio(0);
    FENCE();
    if (t + 2 < nkt) asm volatile("s_waitcnt vmcnt(6)" ::: "memory");
    else             asm volatile("s_waitcnt vmcnt(0)" ::: "memory");
    PH_BAR();
  }

  #pragma unroll
  for (int mr = 0; mr < 8; ++mr) {
    const int gr0 = m0 + wm * 128 + mr * 16 + (lane >> 4) * 4;
    #pragma unroll
    for (int nc = 0; nc < 4; ++nc) {
      const int gc = n0 + wn * 64 + nc * 16 + (lane & 15);
      #pragma unroll
      for (int r = 0; r < 4; ++r) {
        const long off = (long)(gr0 + r) * ldc + gc;
        const float v = acc[mr][nc][r];
        if (EPI == EP_STOREF)      ((float*)C)[off] = v;
        else if (EPI == EP_STOREB) ((bf16*)C)[off] = (bf16)v;
      }
    }
  }
}

// ============================================================================
// Fused flash-style attention (mask-before-softmax, fixed-shift M=0 algebra).
// Round-10 version (best measured) — separate Ps buffer, 99 KB LDS, 1 block/CU.
// ============================================================================
__global__ __launch_bounds__(256, 1)
void flash_attn(const bf16* __restrict__ qb, const bf16* __restrict__ kb,
                const bf16* __restrict__ vT, const float* __restrict__ suffPc,
                bf16* __restrict__ yb, float scale)
{
  __shared__ bf16 Ks[128 * 128];
  __shared__ bf16 Vs[128 * 128];
  __shared__ bf16 Ps[128 * 136];

  const int tid  = (int)threadIdx.x;
  const int lane = tid & 63;
  const int w    = tid >> 6;
  const int qt   = (int)blockIdx.x;
  const int h    = (int)blockIdx.y;
  const int kvh  = h >> 2;

  const int l15 = lane & 15;
  const int g4  = lane >> 4;

  bf16x8 qf[2][4];
  #pragma unroll
  for (int m = 0; m < 2; ++m)
    #pragma unroll
    for (int ks = 0; ks < 4; ++ks)
      qf[m][ks] = *(const bf16x8*)(qb + (long)(qt * 128 + w * 32 + m * 16 + l15) * DMODEL
                                   + h * HDIM + ks * 32 + g4 * 8);

  f32x4 acc_o[2][8] = {};
  float den[2][4] = {};

  const bf16* Kg = kb + (long)kvh * HDIM;
  const bf16* Vg = vT + (long)(kvh * HDIM) * SQ;

  for (int j = 0; j <= qt; ++j) {
    const bool diag = (j == qt);
    PH_BAR();

    #pragma unroll
    for (int i = 0; i < 8; ++i) {
      const int rb = w * 32 + i * 4;
      const int r  = rb + g4;
      GLD(Kg + (long)(j * 128 + r) * 512 + ((l15 ^ (r & 7)) * 8), Ks + rb * 128);
    }
    #pragma unroll
    for (int i = 0; i < 8; ++i) {
      const int rb = w * 32 + i * 4;
      const int r  = rb + g4;
      GLD(Vg + (long)r * SQ + j * 128 + ((l15 ^ (r & 7)) * 8), Vs + rb * 128);
    }
    asm volatile("s_waitcnt vmcnt(8)" ::: "memory");
    PH_BAR();

    f32x4 acc_s[2][8] = {};
    #pragma unroll
    for (int ks = 0; ks < 4; ++ks) {
      bf16x8 kf[8];
      #pragma unroll
      for (int n = 0; n < 8; ++n) {
        const int kr = n * 16 + l15;
        kf[n] = *(const bf16x8*)((const char*)Ks + kr * 256 + (((ks * 4 + g4) ^ (kr & 7)) * 16));
      }
      #pragma unroll
      for (int m = 0; m < 2; ++m)
        #pragma unroll
        for (int n = 0; n < 8; ++n)
          acc_s[m][n] = MFMA16(qf[m][ks], kf[n], acc_s[m][n]);
    }

    float rs[2][4] = {};
    #pragma unroll
    for (int m = 0; m < 2; ++m)
      #pragma unroll
      for (int n = 0; n < 8; ++n) {
        const int kc = n * 16 + l15;
        #pragma unroll
        for (int r = 0; r < 4; ++r) {
          const int qlr = w * 32 + m * 16 + g4 * 4 + r;
          float p = __expf(acc_s[m][n][r] * scale);
          if (diag && kc > qlr) p = 1.0f;
          rs[m][r] += p;
          Ps[(w * 32 + m * 16 + g4 * 4 + r) * 136 + kc] = (bf16)p;
        }
      }
    #pragma unroll
    for (int m = 0; m < 2; ++m)
      #pragma unroll
      for (int r = 0; r < 4; ++r) {
        float v = rs[m][r];
        v += __shfl_xor(v, 1); v += __shfl_xor(v, 2);
        v += __shfl_xor(v, 4); v += __shfl_xor(v, 8);
        den[m][r] += v;
      }

    asm volatile("s_waitcnt vmcnt(0) lgkmcnt(0)" ::: "memory");
    PH_BAR();

    #pragma unroll
    for (int ks = 0; ks < 4; ++ks) {
      bf16x8 pa[2], vf[8];
      #pragma unroll
      for (int m = 0; m < 2; ++m)
        pa[m] = *(const bf16x8*)((const char*)Ps + (w * 32 + m * 16 + l15) * 272
                                 + ks * 64 + g4 * 16);
      #pragma unroll
      for (int n = 0; n < 8; ++n) {
        const int dr = n * 16 + l15;
        vf[n] = *(const bf16x8*)((const char*)Vs + dr * 256 + (((ks * 4 + g4) ^ (dr & 7)) * 16));
      }
      #pragma unroll
      for (int m = 0; m < 2; ++m)
        #pragma unroll
        for (int n = 0; n < 8; ++n)
          acc_o[m][n] = MFMA16(pa[m], vf[n], acc_o[m][n]);
    }
  }

  float denf[2][4];
  #pragma unroll
  for (int m = 0; m < 2; ++m)
    #pragma unroll
    for (int r = 0; r < 4; ++r)
      denf[m][r] = den[m][r] + 128.0f * (15 - qt);

  #pragma unroll
  for (int n = 0; n < 8; ++n) {
    const float t = suffPc[((kvh << 4) + qt) * 128 + n * 16 + l15];
    #pragma unroll
    for (int m = 0; m < 2; ++m)
      #pragma unroll
      for (int r = 0; r < 4; ++r) {
        const float y = (acc_o[m][n][r] + t) / denf[m][r];
        yb[(long)(qt * 128 + w * 32 + m * 16 + g4 * 4 + r) * DMODEL
           + h * HDIM + n * 16 + l15] = (bf16)y;
      }
  }
}

// chunk column sums: chunkS[kvh][c][d] = sum_{s in chunk c} V[s][d]
__global__ __launch_bounds__(128)
void vchunksum(const bf16* __restrict__ vT, float* __restrict__ chunkS)
{
  const int kvh = (int)blockIdx.x;
  const int c   = (int)blockIdx.y;
  const int d   = (int)threadIdx.x;
  const bf16* row = vT + (long)(kvh * HDIM + d) * SQ + c * 128;
  float s = 0.f;
  #pragma unroll
  for (int r = 0; r < 16; ++r) {
    bf16x8 v = *(const bf16x8*)(row + r * 8);
    #pragma unroll
    for (int e = 0; e < 8; ++e) s += (float)v[e];
  }
  chunkS[(kvh * 16 + c) * 128 + d] = s;
}

// suffix scan over the 16 chunk sums
__global__ __launch_bounds__(128)
void vsuffscan(const float* __restrict__ chunkS, float* __restrict__ suffPc)
{
  const int kvh = (int)blockIdx.x;
  const int d   = (int)threadIdx.x;
  float a = 0.f;
  for (int c = 15; c >= 0; --c) {
    suffPc[(kvh * 16 + c) * 128 + d] = a;
    a += chunkS[(kvh * 16 + c) * 128 + d];
  }
}

// fp32 [K][N] -> bf16 transpose+convert, up to 4 segments (z-indexed).
__global__ __launch_bounds__(256)
void transpose_cvt4(const float* __restrict__ s0, bf16* __restrict__ d0, int N0, int L0,
                    const float* __restrict__ s1, bf16* __restrict__ d1, int N1, int L1,
                    const float* __restrict__ s2, bf16* __restrict__ d2, int N2, int L2,
                    const float* __restrict__ s3, bf16* __restrict__ d3, int N3, int L3,
                    int K)
{
  const float* src; bf16* dst; int N, L;
  if (blockIdx.z == 0)      { src = s0; dst = d0; N = N0; L = L0; }
  else if (blockIdx.z == 1) { src = s1; dst = d1; N = N1; L = L1; }
  else if (blockIdx.z == 2) { src = s2; dst = d2; N = N2; L = L2; }
  else                      { src = s3; dst = d3; N = N3; L = L3; }
  if (!src) return;
  const int n0 = (int)blockIdx.x * 32; if (n0 >= N) return;
  const int k0 = (int)blockIdx.y * 32;
  __shared__ float t[32][33];
  const int tr = (int)threadIdx.x >> 3;
  const int tc = ((int)threadIdx.x & 7) * 4;
  f32x4 v = *(const f32x4*)(src + (long)(k0 + tr) * N + n0 + tc);
  t[tr][tc] = v[0]; t[tr][tc + 1] = v[1]; t[tr][tc + 2] = v[2]; t[tr][tc + 3] = v[3];
  __syncthreads();
  bf16x4 b = { (bf16)t[tc][tr], (bf16)t[tc + 1][tr], (bf16)t[tc + 2][tr], (bf16)t[tc + 3][tr] };
  *(bf16x4*)(dst + (long)(n0 + tr) * L + k0 + tc) = b;
}

__global__ __launch_bounds__(256)
void cvt_bf16_kernel(const float* __restrict__ in, bf16* __restrict__ out, int nvec)
{
  const int i = (int)(blockIdx.x * 256 + threadIdx.x);
  if (i < nvec) {
    f32x4 v = ((const f32x4*)in)[i];
    bf16x4 b = { (bf16)v[0], (bf16)v[1], (bf16)v[2], (bf16)v[3] };
    ((bf16x4*)out)[i] = b;
  }
}

__global__ __launch_bounds__(256)
void rmsnorm_kernel(bf16* __restrict__ out, const float* __restrict__ in, const float* __restrict__ g)
{
  const int row = (int)blockIdx.x;
  const float* x = in + (long)row * DMODEL;
  bf16* o = out + (long)row * DMODEL;
  const int tid = (int)threadIdx.x;
  f32x4 v0 = *(const f32x4*)(x + tid * 4);
  f32x4 v1 = *(const f32x4*)(x + tid * 4 + 1024);
  float ss = v0[0]*v0[0] + v0[1]*v0[1] + v0[2]*v0[2] + v0[3]*v0[3]
           + v1[0]*v1[0] + v1[1]*v1[1] + v1[2]*v1[2] + v1[3]*v1[3];
  #pragma unroll
  for (int o_ = 32; o_; o_ >>= 1) ss += __shfl_xor(ss, o_);
  __shared__ float sm[4];
  if ((tid & 63) == 0) sm[tid >> 6] = ss;
  __syncthreads();
  ss = sm[0] + sm[1] + sm[2] + sm[3];
  const float r = 1.0f / sqrtf(ss * (1.0f / DMODEL) + EPSV);
  f32x4 g0 = *(const f32x4*)(g + tid * 4);
  f32x4 g1 = *(const f32x4*)(g + tid * 4 + 1024);
  bf16x4 o0, o1;
  #pragma unroll
  for (int j = 0; j < 4; ++j) { o0[j] = (bf16)(v0[j] * r * g0[j]); o1[j] = (bf16)(v1[j] * r * g1[j]); }
  *(bf16x4*)(o + tid * 4) = o0;
  *(bf16x4*)(o + tid * 4 + 1024) = o1;
}

__global__ void rope_tables(float* cosT, float* sinT)
{
  const int s = (int)blockIdx.x;
  const int i = (int)threadIdx.x;
  const double inv = pow(10000.0, -(double)i / 64.0);
  const double f = (double)s * inv;
  cosT[s * 64 + i] = (float)cos(f);
  sinT[s * 64 + i] = (float)sin(f);
}

__global__ __launch_bounds__(256)
void embed_gather(f32x4* x, const f32x4* embed, const int* idx)
{
  const int t = (int)(blockIdx.x * 256 + threadIdx.x);
  const int s = t >> 9;
  const int c = t & 511;
  x[t] = embed[(long)idx[s] * 512 + c];
}

extern "C" void kernel_launch(void* const* d_in, const int* in_sizes, int n_in,
                              void* d_out, int out_size, void* d_ws, size_t ws_size,
                              hipStream_t stream)
{
  (void)in_sizes; (void)n_in; (void)out_size;
  const int*   idx   = (const int*)  d_in[0];
  const float* embed = (const float*)d_in[1];
  const float* wq    = (const float*)d_in[2];
  const float* wk    = (const float*)d_in[3];
  const float* wv    = (const float*)d_in[4];
  const float* wo    = (const float*)d_in[5];
  const float* ln1g  = (const float*)d_in[6];
  const float* ln2g  = (const float*)d_in[7];
  const float* wgate = (const float*)d_in[8];
  const float* wup   = (const float*)d_in[9];
  const float* wdown = (const float*)d_in[10];
  const float* fing  = (const float*)d_in[11];
  const float* lmh   = (const float*)d_in[12];
  float* out = (float*)d_out;

  char* wp = (char*)d_ws;
  auto alloc = [&](size_t bytes) { char* p = wp; wp += (bytes + 255) & ~(size_t)255; return p; };
  float* cosT   = (float*)alloc((size_t)SQ * 64 * 4);
  float* sinT   = (float*)alloc((size_t)SQ * 64 * 4);
  float* suffPc = (float*)alloc((size_t)NKV * 16 * 128 * 4);
  float* chunkS = (float*)alloc((size_t)NKV * 16 * 128 * 4);
  float* x      = (float*)alloc((size_t)SQ * DMODEL * 4);
  bf16*  h      = (bf16*) alloc((size_t)SQ * DMODEL * 2);
  bf16*  qb     = (bf16*) alloc((size_t)SQ * DMODEL * 2);
  bf16*  kb     = (bf16*) alloc((size_t)SQ * 512 * 2);
  bf16*  vT     = (bf16*) alloc((size_t)512 * SQ * 2);
  bf16*  ffb    = (bf16*) alloc((size_t)SQ * FFDIM * 2);
  size_t used  = (size_t)(wp - (char*)d_ws);
  bf16*  wbuf  = (bf16*)wp;                 // weight scratch (peak: gate+up 46 MB)
  size_t avail = ws_size - used;

  bf16* yb = qb;                            // flash writes y over q (same rows per block)
  const float scale = 0.08838834764831845f;

  rope_tables<<<SQ, 64, 0, stream>>>(cosT, sinT);
  embed_gather<<<(SQ * 512) / 256, 256, 0, stream>>>((f32x4*)x, (const f32x4*)embed, idx);

  for (int l = 0; l < NLAYER; ++l) {
    const float* lwq = wq    + (long)l * DMODEL * DMODEL;
    const float* lwk = wk    + (long)l * DMODEL * 512;
    const float* lwv = wv    + (long)l * DMODEL * 512;
    const float* lwo = wo    + (long)l * DMODEL * DMODEL;
    const float* lwg = wgate + (long)l * DMODEL * FFDIM;
    const float* lwu = wup   + (long)l * DMODEL * FFDIM;
    const float* lwd = wdown + (long)l * FFDIM * DMODEL;

    rmsnorm_kernel<<<SQ, 256, 0, stream>>>(h, x, ln1g + l * DMODEL);

    // QKV + wo weight cvt in one dispatch: [wq^T | wk^T | wv^T | wo^T] (5120 x 2048, 21 MB)
    bf16* wob = wbuf + (long)3072 * DMODEL;
    transpose_cvt4<<<dim3(64, 64, 4), 256, 0, stream>>>(
        lwq, wbuf, DMODEL, DMODEL,
        lwk, wbuf + (long)2048 * DMODEL, 512, DMODEL,
        lwv, wbuf + (long)2560 * DMODEL, 512, DMODEL,
        lwo, wob, DMODEL, DMODEL, DMODEL);
    // QKV GEMM with in-epilogue RoPE for q and k
    gemm128<EP_QKV, 2><<<dim3(16, 24), 256, 0, stream>>>(
        h, wbuf, qb, nullptr, kb, vT, cosT, sinT, DMODEL, DMODEL, DMODEL, 0);

    vchunksum<<<dim3(NKV, 16), 128, 0, stream>>>(vT, chunkS);
    vsuffscan<<<NKV, 128, 0, stream>>>(chunkS, suffPc);

    flash_attn<<<dim3(16, NHEAD), 256, 0, stream>>>(qb, kb, vT, suffPc, yb, scale);

    // x += y @ wo  — split-K=2, fp32 atomics into x (in place)
    gemm128<EP_ATOMIC, 2><<<dim3(16, 16, 2), 256, 0, stream>>>(
        yb, wob, x, nullptr, nullptr, nullptr, nullptr, nullptr,
        DMODEL, DMODEL, DMODEL, DMODEL);

    rmsnorm_kernel<<<SQ, 256, 0, stream>>>(h, x, ln2g + l * DMODEL);

    // gate+up interleaved: even rows = wg^T, odd rows = wu^T (11264 x 2048)
    transpose_cvt4<<<dim3(176, 64, 2), 256, 0, stream>>>(
        lwg, wbuf, FFDIM, 2 * DMODEL,
        lwu, wbuf + DMODEL, FFDIM, 2 * DMODEL,
        nullptr, nullptr, 0, 0, nullptr, nullptr, 0, 0, DMODEL);
    gemm128<EP_GLU, 2><<<dim3(16, 88), 256, 0, stream>>>(
        h, wbuf, ffb, nullptr, nullptr, nullptr, nullptr, nullptr,
        DMODEL, DMODEL, DMODEL, FFDIM);

    // x += ffb @ w_down — split-K=2, fp32 atomics into x (in place)
    transpose_cvt4<<<dim3(64, 176, 1), 256, 0, stream>>>(
        lwd, wbuf, DMODEL, FFDIM,
        nullptr, nullptr, 0, 0, nullptr, nullptr, 0, 0,
        nullptr, nullptr, 0, 0, FFDIM);
    gemm128<EP_ATOMIC, 2><<<dim3(16, 16, 2), 256, 0, stream>>>(
        ffb, wbuf, x, nullptr, nullptr, nullptr, nullptr, nullptr,
        FFDIM, FFDIM, FFDIM, DMODEL);
  }

  rmsnorm_kernel<<<SQ, 256, 0, stream>>>(h, x, fing);

  long chunkRows = (long)(avail / ((size_t)DMODEL * 2)) & ~255L;
  if (chunkRows > VOCAB) chunkRows = VOCAB;
  for (long c0 = 0; c0 < VOCAB; c0 += chunkRows) {
    const long rows = (VOCAB - c0 < chunkRows) ? (VOCAB - c0) : chunkRows;
    const int  nvec = (int)(rows * DMODEL / 4);
    cvt_bf16_kernel<<<(nvec + 255) / 256, 256, 0, stream>>>(lmh + c0 * DMODEL, wbuf, nvec);
    gemm256<EP_STOREF><<<dim3(8, (int)(rows / 256)), 512, 0, stream>>>(
        h, wbuf, out + c0, nullptr, DMODEL, DMODEL, DMODEL, VOCAB);
  }
}